// Round 1
// baseline (979.223 us; speedup 1.0000x reference)
//
#include <hip/hip_runtime.h>
#include <cstdio>

// MoE top-2 FFN: B=4,S=2048,D=1024 -> T=8192 tokens; E=8, H=4096, K_TOP=2.
// Pipeline: router(fp32) -> padded prefix offsets -> scatter -> gather(x->bf16)
//           -> GEMM1 (xg @ W1^T, gelu) -> GEMM2 (h @ W2^T, *weight) -> combine.
// All-expert math is masked in the reference; we compute only the top-2 pairs.

#define T_TOK 8192
#define DIM   1024
#define NEXP  8
#define HID   4096
#define MAXR  17408  // 16384 rows + 8 experts * 127 pad, multiple of 128

typedef float          f32x4   __attribute__((ext_vector_type(4)));
typedef short          bf16x8  __attribute__((ext_vector_type(8)));
typedef unsigned short u16x8   __attribute__((ext_vector_type(8)));
typedef unsigned short u16x4   __attribute__((ext_vector_type(4)));

static __device__ __forceinline__ unsigned short f2bf(float f) {
  unsigned int u = __builtin_bit_cast(unsigned int, f);
  u = (u + 0x7FFFu + ((u >> 16) & 1u)) >> 16;   // round-nearest-even (finite inputs)
  return (unsigned short)u;
}

// ---------------- router: logits, top-2, normalized weights, counts ----------
__global__ __launch_bounds__(256) void router_k(const float* __restrict__ x,
                                                const float* __restrict__ Wr,
                                                const float* __restrict__ br,
                                                int* __restrict__ meta,
                                                int2* __restrict__ top_i,
                                                float2* __restrict__ top_w) {
  int lane = threadIdx.x & 63;
  int wid  = threadIdx.x >> 6;
  int t = blockIdx.x * 4 + wid;                  // grid = T/4
  const float* xp = x + (size_t)t * DIM + lane * 16;
  float acc[NEXP];
#pragma unroll
  for (int e = 0; e < NEXP; ++e) acc[e] = 0.f;
#pragma unroll
  for (int j = 0; j < 16; j += 4) {
    float4 xv = *(const float4*)(xp + j);
    const float* wp = Wr + (size_t)(lane * 16 + j) * NEXP;
#pragma unroll
    for (int jj = 0; jj < 4; ++jj) {
      float xs = jj == 0 ? xv.x : jj == 1 ? xv.y : jj == 2 ? xv.z : xv.w;
      float4 w0 = *(const float4*)(wp + jj * NEXP);
      float4 w1 = *(const float4*)(wp + jj * NEXP + 4);
      acc[0] += xs * w0.x; acc[1] += xs * w0.y; acc[2] += xs * w0.z; acc[3] += xs * w0.w;
      acc[4] += xs * w1.x; acc[5] += xs * w1.y; acc[6] += xs * w1.z; acc[7] += xs * w1.w;
    }
  }
#pragma unroll
  for (int off = 32; off > 0; off >>= 1) {
#pragma unroll
    for (int e = 0; e < NEXP; ++e) acc[e] += __shfl_xor(acc[e], off);
  }
  if (lane == 0) {
    float l[NEXP];
#pragma unroll
    for (int e = 0; e < NEXP; ++e) l[e] = acc[e] + br[e];
    int e1 = 0;
#pragma unroll
    for (int e = 1; e < NEXP; ++e) if (l[e] > l[e1]) e1 = e;      // ties -> lower idx
    int e2 = (e1 == 0) ? 1 : 0;
#pragma unroll
    for (int e = 0; e < NEXP; ++e) if (e != e1 && l[e] > l[e2]) e2 = e;
    float g  = expf(l[e2] - l[e1]);              // softmax over top-2 == renorm of full softmax
    float w1 = 1.f / (1.f + g);
    top_i[t] = make_int2(e1, e2);
    top_w[t] = make_float2(w1, 1.f - w1);
    atomicAdd(&meta[e1], 1);
    atomicAdd(&meta[e2], 1);
  }
}

// -------- setup: padded (x128) prefix offsets + default-fill row arrays ------
__global__ void setup_k(int* __restrict__ meta,
                        int* __restrict__ tok_of_row,
                        float* __restrict__ wt_of_row) {
  if (threadIdx.x == 0) {
    int s = 0;
#pragma unroll
    for (int e = 0; e < NEXP; ++e) {
      meta[16 + e] = s;                          // poff[e]
      s += (meta[e] + 127) & ~127;
    }
    meta[24] = s;                                // poff[8]
    meta[25] = s;                                // total_padded (<= MAXR always)
  }
  for (int i = threadIdx.x; i < MAXR; i += 256) {  // pad rows: token 0, weight 0
    tok_of_row[i] = 0;
    wt_of_row[i] = 0.f;
  }
}

// ---------------- scatter: token -> packed expert row ------------------------
__global__ __launch_bounds__(256) void scatter_k(const int2* __restrict__ top_i,
                                                 const float2* __restrict__ top_w,
                                                 int* __restrict__ meta,
                                                 int* __restrict__ row_of,
                                                 int* __restrict__ tok_of_row,
                                                 float* __restrict__ wt_of_row) {
  int t = blockIdx.x * 256 + threadIdx.x;
  int2  ei = top_i[t];
  float2 w = top_w[t];
  int p = atomicAdd(&meta[8 + ei.x], 1);
  int r = meta[16 + ei.x] + p;
  tok_of_row[r] = t; wt_of_row[r] = w.x; row_of[t * 2] = r;
  p = atomicAdd(&meta[8 + ei.y], 1);
  r = meta[16 + ei.y] + p;
  tok_of_row[r] = t; wt_of_row[r] = w.y; row_of[t * 2 + 1] = r;
}

// ---------------- gather: xg[r][:] = bf16(x[tok[r]][:]) ----------------------
__global__ __launch_bounds__(256) void gather_k(const float* __restrict__ x,
                                                const int* __restrict__ tok_of_row,
                                                const int* __restrict__ meta,
                                                unsigned short* __restrict__ xg) {
  int r = blockIdx.x;
  if (r >= meta[25]) return;
  int t = tok_of_row[r];
  int c = threadIdx.x * 4;
  float4 v = *(const float4*)(x + (size_t)t * DIM + c);
  u16x4 o;
  o[0] = f2bf(v.x); o[1] = f2bf(v.y); o[2] = f2bf(v.z); o[3] = f2bf(v.w);
  *(u16x4*)(xg + (size_t)r * DIM + c) = o;
}

// -------- transpose + fp32->bf16: W[e][R][C] -> WT[e][C][R] ------------------
__global__ __launch_bounds__(256) void transpose_convert_k(const float* __restrict__ W,
                                                           unsigned short* __restrict__ WT,
                                                           int R, int C) {
  __shared__ float tile[32][33];
  int e = blockIdx.z;
  int c0 = blockIdx.x * 32, r0 = blockIdx.y * 32;
  const float* Wp = W + (size_t)e * R * C;
  unsigned short* Op = WT + (size_t)e * R * C;
  int tr = threadIdx.x >> 3;
  int tc = (threadIdx.x & 7) * 4;
  float4 v = *(const float4*)(Wp + (size_t)(r0 + tr) * C + c0 + tc);
  tile[tr][tc] = v.x; tile[tr][tc + 1] = v.y; tile[tr][tc + 2] = v.z; tile[tr][tc + 3] = v.w;
  __syncthreads();
  int oc  = threadIdx.x >> 3;
  int orr = (threadIdx.x & 7) * 4;
  u16x4 o;
#pragma unroll
  for (int j = 0; j < 4; ++j) o[j] = f2bf(tile[orr + j][oc]);
  *(u16x4*)(Op + (size_t)(c0 + oc) * R + r0 + orr) = o;
}

// ---------------- grouped GEMM: C = A[128-row tile] @ Bt[e]^T ----------------
// A: [M][KTOT] bf16 (packed rows).  Bt: [E][NTOT][KTOT] bf16 (pre-transposed).
// EPI 0: h = bf16(gelu(acc + b1[e][n]))     EPI 1: y = f32((acc + b2[e][n]) * wt[m])
template <int KTOT, int NTOT, int EPI>
__global__ __launch_bounds__(256) void gemm_k(const unsigned short* __restrict__ A,
                                              const unsigned short* __restrict__ Bt,
                                              const float* __restrict__ bias,
                                              const int* __restrict__ meta,
                                              const float* __restrict__ wt_of_row,
                                              void* __restrict__ Cout) {
  int row0 = blockIdx.x * 128;
  if (row0 >= meta[25]) return;                  // beyond padded total
  int n0 = blockIdx.y * 128;
  int e = 0;
  while (meta[17 + e] <= row0) ++e;              // tiles never straddle experts
  const unsigned short* Bp = Bt + (size_t)e * NTOT * KTOT;

  __shared__ __align__(16) unsigned short Ash[128 * 32];
  __shared__ __align__(16) unsigned short Bsh[128 * 32];

  int tid = threadIdx.x;
  int lane = tid & 63, wid = tid >> 6;
  int wm = wid >> 1, wn = wid & 1;               // 2x2 waves, 64x64 each
  int r_lo = tid >> 2;                           // staging row 0..63
  int colu = (tid & 3) * 8;                      // staging col (ushorts)

  const unsigned short* Ap0 = A + (size_t)(row0 + r_lo) * KTOT + colu;
  const unsigned short* Ap1 = Ap0 + (size_t)64 * KTOT;
  const unsigned short* Bp0 = Bp + (size_t)(n0 + r_lo) * KTOT + colu;
  const unsigned short* Bp1 = Bp0 + (size_t)64 * KTOT;
  unsigned short* asw = Ash + r_lo * 32 + colu;
  unsigned short* bsw = Bsh + r_lo * 32 + colu;

  f32x4 acc[4][4];
#pragma unroll
  for (int i = 0; i < 4; ++i)
#pragma unroll
    for (int j = 0; j < 4; ++j) acc[i][j] = (f32x4){0.f, 0.f, 0.f, 0.f};

  int am = lane & 15, ak = (lane >> 4) * 8;      // frag: m/n = lane&15, k = (lane>>4)*8 + j

  for (int kt = 0; kt < KTOT / 32; ++kt) {
    u16x8 a0 = *(const u16x8*)(Ap0 + kt * 32);
    u16x8 a1 = *(const u16x8*)(Ap1 + kt * 32);
    u16x8 b0 = *(const u16x8*)(Bp0 + kt * 32);
    u16x8 b1 = *(const u16x8*)(Bp1 + kt * 32);
    __syncthreads();
    *(u16x8*)asw = a0;
    *(u16x8*)(asw + 64 * 32) = a1;
    *(u16x8*)bsw = b0;
    *(u16x8*)(bsw + 64 * 32) = b1;
    __syncthreads();
    bf16x8 af[4], bfr[4];
#pragma unroll
    for (int i = 0; i < 4; ++i)
      af[i] = *(const bf16x8*)(Ash + (wm * 64 + i * 16 + am) * 32 + ak);
#pragma unroll
    for (int j = 0; j < 4; ++j)
      bfr[j] = *(const bf16x8*)(Bsh + (wn * 64 + j * 16 + am) * 32 + ak);
#pragma unroll
    for (int i = 0; i < 4; ++i)
#pragma unroll
      for (int j = 0; j < 4; ++j)
        acc[i][j] = __builtin_amdgcn_mfma_f32_16x16x32_bf16(af[i], bfr[j], acc[i][j], 0, 0, 0);
  }

  // C/D layout (verified): col n = lane&15, row m = (lane>>4)*4 + reg
  int rbase = row0 + wm * 64 + (lane >> 4) * 4;
  int nbase = n0 + wn * 64 + (lane & 15);
  if constexpr (EPI == 0) {
    unsigned short* Hp = (unsigned short*)Cout;
    const float* bp = bias + (size_t)e * NTOT;
#pragma unroll
    for (int i = 0; i < 4; ++i) {
#pragma unroll
      for (int j = 0; j < 4; ++j) {
        int n = nbase + j * 16;
        float bv = bp[n];
#pragma unroll
        for (int rg = 0; rg < 4; ++rg) {
          int m = rbase + i * 16 + rg;
          float v = acc[i][j][rg] + bv;
          v = 0.5f * v * (1.f + erff(v * 0.70710678118654752f));   // exact gelu
          Hp[(size_t)m * NTOT + n] = f2bf(v);
        }
      }
    }
  } else {
    float* Yp = (float*)Cout;
    const float* bp = bias + (size_t)e * NTOT;
#pragma unroll
    for (int i = 0; i < 4; ++i) {
#pragma unroll
      for (int rg = 0; rg < 4; ++rg) {
        int m = rbase + i * 16 + rg;
        float wt = wt_of_row[m];
#pragma unroll
        for (int j = 0; j < 4; ++j) {
          int n = nbase + j * 16;
          Yp[(size_t)m * NTOT + n] = (acc[i][j][rg] + bp[n]) * wt;
        }
      }
    }
  }
}

// ---------------- combine: out[t] = y[row0(t)] + y[row1(t)] ------------------
__global__ __launch_bounds__(256) void combine_k(const float* __restrict__ y,
                                                 const int* __restrict__ row_of,
                                                 float* __restrict__ out) {
  int t = blockIdx.x;
  int r0 = row_of[t * 2], r1 = row_of[t * 2 + 1];
  int c = threadIdx.x * 4;
  float4 a = *(const float4*)(y + (size_t)r0 * DIM + c);
  float4 b = *(const float4*)(y + (size_t)r1 * DIM + c);
  *(float4*)(out + (size_t)t * DIM + c) =
      make_float4(a.x + b.x, a.y + b.y, a.z + b.z, a.w + b.w);
}

extern "C" void kernel_launch(void* const* d_in, const int* in_sizes, int n_in,
                              void* d_out, int out_size, void* d_ws, size_t ws_size,
                              hipStream_t stream) {
  const float* x  = (const float*)d_in[0];
  const float* Wr = (const float*)d_in[1];
  const float* br = (const float*)d_in[2];
  const float* W1 = (const float*)d_in[3];
  const float* b1 = (const float*)d_in[4];
  const float* W2 = (const float*)d_in[5];
  const float* b2 = (const float*)d_in[6];
  float* out = (float*)d_out;

  char* base = (char*)d_ws;
  size_t off = 0;
  auto carve = [&](size_t bytes) -> void* {
    void* r = base + off;
    off = (off + bytes + 255) & ~(size_t)255;
    return r;
  };
  int*            meta       = (int*)carve(26 * 4);
  int2*           top_i      = (int2*)carve((size_t)T_TOK * 8);
  float2*         top_w      = (float2*)carve((size_t)T_TOK * 8);
  int*            row_of     = (int*)carve((size_t)T_TOK * 2 * 4);
  int*            tok_of_row = (int*)carve((size_t)MAXR * 4);
  float*          wt_of_row  = (float*)carve((size_t)MAXR * 4);
  unsigned short* xg         = (unsigned short*)carve((size_t)MAXR * DIM * 2);
  unsigned short* W1bT       = (unsigned short*)carve((size_t)NEXP * DIM * HID * 2);
  unsigned short* W2bT       = (unsigned short*)carve((size_t)NEXP * DIM * HID * 2);
  unsigned short* hbuf       = (unsigned short*)carve((size_t)MAXR * HID * 2);
  float*          ybuf       = (float*)carve((size_t)MAXR * DIM * 4);
  if (off > ws_size) {
    fprintf(stderr, "kernel_launch: ws_size too small: need %zu have %zu\n", off, ws_size);
    return;
  }

  hipMemsetAsync(meta, 0, 26 * 4, stream);
  hipLaunchKernelGGL(transpose_convert_k, dim3(HID / 32, DIM / 32, NEXP), dim3(256), 0, stream,
                     W1, W1bT, DIM, HID);                 // W1[e][D][H] -> [e][H][D]
  hipLaunchKernelGGL(transpose_convert_k, dim3(DIM / 32, HID / 32, NEXP), dim3(256), 0, stream,
                     W2, W2bT, HID, DIM);                 // W2[e][H][D] -> [e][D][H]
  hipLaunchKernelGGL(router_k, dim3(T_TOK / 4), dim3(256), 0, stream,
                     x, Wr, br, meta, top_i, top_w);
  hipLaunchKernelGGL(setup_k, dim3(1), dim3(256), 0, stream, meta, tok_of_row, wt_of_row);
  hipLaunchKernelGGL(scatter_k, dim3(T_TOK / 256), dim3(256), 0, stream,
                     top_i, top_w, meta, row_of, tok_of_row, wt_of_row);
  hipLaunchKernelGGL(gather_k, dim3(MAXR), dim3(256), 0, stream, x, tok_of_row, meta, xg);
  hipLaunchKernelGGL((gemm_k<DIM, HID, 0>), dim3(MAXR / 128, HID / 128), dim3(256), 0, stream,
                     xg, W1bT, b1, meta, wt_of_row, (void*)hbuf);
  hipLaunchKernelGGL((gemm_k<HID, DIM, 1>), dim3(MAXR / 128, DIM / 128), dim3(256), 0, stream,
                     hbuf, W2bT, b2, meta, wt_of_row, (void*)ybuf);
  hipLaunchKernelGGL(combine_k, dim3(T_TOK), dim3(256), 0, stream, ybuf, row_of, out);
}

// Round 2
// 893.706 us; speedup vs baseline: 1.0957x; 1.0957x over previous
//
#include <hip/hip_runtime.h>
#include <cstdio>

// MoE top-2 FFN: B=4,S=2048,D=1024 -> T=8192 tokens; E=8, H=4096, K_TOP=2.
// Pipeline: router(fp32) -> padded prefix offsets -> scatter -> gather(x->bf16)
//           -> GEMM1 (xg @ W1^T, gelu) -> GEMM2 (h @ W2^T, *weight) -> combine.
// Round 2: GEMM staging via global_load_lds width=16 (m97 structure),
//          XCD-swizzled 1D grid, parallel fill kernel.

#define T_TOK 8192
#define DIM   1024
#define NEXP  8
#define HID   4096
#define MAXR  17408  // 16384 rows + 8 experts * 127 pad, multiple of 128

typedef float          f32x4   __attribute__((ext_vector_type(4)));
typedef short          bf16x8  __attribute__((ext_vector_type(8)));
typedef unsigned short u16x8   __attribute__((ext_vector_type(8)));
typedef unsigned short u16x4   __attribute__((ext_vector_type(4)));

static __device__ __forceinline__ unsigned short f2bf(float f) {
  unsigned int u = __builtin_bit_cast(unsigned int, f);
  u = (u + 0x7FFFu + ((u >> 16) & 1u)) >> 16;   // round-nearest-even (finite inputs)
  return (unsigned short)u;
}

// async global->LDS, 16B per lane; LDS dest must be linear in lane order
static __device__ __forceinline__ void gl16(const void* g, void* l) {
  __builtin_amdgcn_global_load_lds(
      (const __attribute__((address_space(1))) unsigned int*)g,
      (__attribute__((address_space(3))) unsigned int*)l,
      16, 0, 0);
}

// ---------------- router: logits, top-2, normalized weights, counts ----------
__global__ __launch_bounds__(256) void router_k(const float* __restrict__ x,
                                                const float* __restrict__ Wr,
                                                const float* __restrict__ br,
                                                int* __restrict__ meta,
                                                int2* __restrict__ top_i,
                                                float2* __restrict__ top_w) {
  int lane = threadIdx.x & 63;
  int wid  = threadIdx.x >> 6;
  int t = blockIdx.x * 4 + wid;                  // grid = T/4
  const float* xp = x + (size_t)t * DIM + lane * 16;
  float acc[NEXP];
#pragma unroll
  for (int e = 0; e < NEXP; ++e) acc[e] = 0.f;
#pragma unroll
  for (int j = 0; j < 16; j += 4) {
    float4 xv = *(const float4*)(xp + j);
    const float* wp = Wr + (size_t)(lane * 16 + j) * NEXP;
#pragma unroll
    for (int jj = 0; jj < 4; ++jj) {
      float xs = jj == 0 ? xv.x : jj == 1 ? xv.y : jj == 2 ? xv.z : xv.w;
      float4 w0 = *(const float4*)(wp + jj * NEXP);
      float4 w1 = *(const float4*)(wp + jj * NEXP + 4);
      acc[0] += xs * w0.x; acc[1] += xs * w0.y; acc[2] += xs * w0.z; acc[3] += xs * w0.w;
      acc[4] += xs * w1.x; acc[5] += xs * w1.y; acc[6] += xs * w1.z; acc[7] += xs * w1.w;
    }
  }
#pragma unroll
  for (int off = 32; off > 0; off >>= 1) {
#pragma unroll
    for (int e = 0; e < NEXP; ++e) acc[e] += __shfl_xor(acc[e], off);
  }
  if (lane == 0) {
    float l[NEXP];
#pragma unroll
    for (int e = 0; e < NEXP; ++e) l[e] = acc[e] + br[e];
    int e1 = 0;
#pragma unroll
    for (int e = 1; e < NEXP; ++e) if (l[e] > l[e1]) e1 = e;      // ties -> lower idx
    int e2 = (e1 == 0) ? 1 : 0;
#pragma unroll
    for (int e = 0; e < NEXP; ++e) if (e != e1 && l[e] > l[e2]) e2 = e;
    float g  = expf(l[e2] - l[e1]);              // softmax over top-2 == renorm of full softmax
    float w1 = 1.f / (1.f + g);
    top_i[t] = make_int2(e1, e2);
    top_w[t] = make_float2(w1, 1.f - w1);
    atomicAdd(&meta[e1], 1);
    atomicAdd(&meta[e2], 1);
  }
}

// -------- prefix: padded (x128) offsets (single thread, trivial) -------------
__global__ void prefix_k(int* __restrict__ meta) {
  if (threadIdx.x == 0) {
    int s = 0;
#pragma unroll
    for (int e = 0; e < NEXP; ++e) {
      meta[16 + e] = s;                          // poff[e]
      s += (meta[e] + 127) & ~127;
    }
    meta[24] = s;                                // poff[8]
    meta[25] = s;                                // total_padded (<= MAXR always)
  }
}

// -------- fill: default row arrays (pad rows: token 0, weight 0) -------------
__global__ __launch_bounds__(256) void fill_k(int* __restrict__ tok_of_row,
                                              float* __restrict__ wt_of_row) {
  int i = blockIdx.x * 256 + threadIdx.x;
  if (i < MAXR) { tok_of_row[i] = 0; wt_of_row[i] = 0.f; }
}

// ---------------- scatter: token -> packed expert row ------------------------
__global__ __launch_bounds__(256) void scatter_k(const int2* __restrict__ top_i,
                                                 const float2* __restrict__ top_w,
                                                 int* __restrict__ meta,
                                                 int* __restrict__ row_of,
                                                 int* __restrict__ tok_of_row,
                                                 float* __restrict__ wt_of_row) {
  int t = blockIdx.x * 256 + threadIdx.x;
  int2  ei = top_i[t];
  float2 w = top_w[t];
  int p = atomicAdd(&meta[8 + ei.x], 1);
  int r = meta[16 + ei.x] + p;
  tok_of_row[r] = t; wt_of_row[r] = w.x; row_of[t * 2] = r;
  p = atomicAdd(&meta[8 + ei.y], 1);
  r = meta[16 + ei.y] + p;
  tok_of_row[r] = t; wt_of_row[r] = w.y; row_of[t * 2 + 1] = r;
}

// ---------------- gather: xg[r][:] = bf16(x[tok[r]][:]) ----------------------
__global__ __launch_bounds__(256) void gather_k(const float* __restrict__ x,
                                                const int* __restrict__ tok_of_row,
                                                const int* __restrict__ meta,
                                                unsigned short* __restrict__ xg) {
  int r = blockIdx.x;
  if (r >= meta[25]) return;
  int t = tok_of_row[r];
  int c = threadIdx.x * 4;
  float4 v = *(const float4*)(x + (size_t)t * DIM + c);
  u16x4 o;
  o[0] = f2bf(v.x); o[1] = f2bf(v.y); o[2] = f2bf(v.z); o[3] = f2bf(v.w);
  *(u16x4*)(xg + (size_t)r * DIM + c) = o;
}

// -------- transpose + fp32->bf16: W[e][R][C] -> WT[e][C][R] ------------------
__global__ __launch_bounds__(256) void transpose_convert_k(const float* __restrict__ W,
                                                           unsigned short* __restrict__ WT,
                                                           int R, int C) {
  __shared__ float tile[32][33];
  int e = blockIdx.z;
  int c0 = blockIdx.x * 32, r0 = blockIdx.y * 32;
  const float* Wp = W + (size_t)e * R * C;
  unsigned short* Op = WT + (size_t)e * R * C;
  int tr = threadIdx.x >> 3;
  int tc = (threadIdx.x & 7) * 4;
  float4 v = *(const float4*)(Wp + (size_t)(r0 + tr) * C + c0 + tc);
  tile[tr][tc] = v.x; tile[tr][tc + 1] = v.y; tile[tr][tc + 2] = v.z; tile[tr][tc + 3] = v.w;
  __syncthreads();
  int oc  = threadIdx.x >> 3;
  int orr = (threadIdx.x & 7) * 4;
  u16x4 o;
#pragma unroll
  for (int j = 0; j < 4; ++j) o[j] = f2bf(tile[orr + j][oc]);
  *(u16x4*)(Op + (size_t)(c0 + oc) * R + r0 + orr) = o;
}

// ---------------- grouped GEMM: C = A[128-row tile] @ Bt[e]^T ----------------
// A: [M][KTOT] bf16 (packed rows).  Bt: [E][NTOT][KTOT] bf16 (pre-transposed).
// m97 structure: 128x128 tile, BK=32, 4 waves, global_load_lds width=16.
// EPI 0: h = bf16(gelu(acc + b1[e][n]))     EPI 1: y = f32((acc + b2[e][n]) * wt[m])
template <int KTOT, int NTOT, int EPI>
__global__ __launch_bounds__(256) void gemm_k(const unsigned short* __restrict__ A,
                                              const unsigned short* __restrict__ Bt,
                                              const float* __restrict__ bias,
                                              const int* __restrict__ meta,
                                              const float* __restrict__ wt_of_row,
                                              void* __restrict__ Cout) {
  constexpr int NXB = MAXR / 128;                // 136 row tiles
  constexpr int NWG = NXB * (NTOT / 128);        // 4352 or 1088, both % 8 == 0
  // XCD-aware bijective swizzle; x-major within an XCD chunk -> B-panel L2 reuse
  int id = (blockIdx.x & 7) * (NWG / 8) + (blockIdx.x >> 3);
  int row0 = (id % NXB) * 128;
  int n0   = (id / NXB) * 128;
  if (row0 >= meta[25]) return;                  // beyond padded total
  int e = 0;
  while (meta[17 + e] <= row0) ++e;              // tiles never straddle experts
  const unsigned short* Bp = Bt + (size_t)e * NTOT * KTOT;

  __shared__ __align__(16) unsigned short Ash[128 * 32];
  __shared__ __align__(16) unsigned short Bsh[128 * 32];

  int tid = threadIdx.x;
  int lane = tid & 63, wid = tid >> 6;
  int wm = wid >> 1, wn = wid & 1;               // 2x2 waves, 64x64 each
  int rs = tid >> 2;                             // staging row 0..63
  int cs = (tid & 3) * 8;                        // staging col (ushorts)

  const unsigned short* Ag = A  + (size_t)(row0 + rs) * KTOT + cs;
  const unsigned short* Bg = Bp + (size_t)(n0   + rs) * KTOT + cs;
  unsigned short* Al = Ash + tid * 8;            // linear: row*32 + col == tid*8
  unsigned short* Bl = Bsh + tid * 8;

  f32x4 acc[4][4];
#pragma unroll
  for (int i = 0; i < 4; ++i)
#pragma unroll
    for (int j = 0; j < 4; ++j) acc[i][j] = (f32x4){0.f, 0.f, 0.f, 0.f};

  int am = lane & 15, ak = (lane >> 4) * 8;      // frag: m/n = lane&15, k = (lane>>4)*8 + j

  for (int kt = 0; kt < KTOT; kt += 32) {
    __syncthreads();                             // prev compute done before overwrite
    gl16(Ag + kt, Al);
    gl16(Ag + 64 * KTOT + kt, Al + 2048);        // rows 64..127
    gl16(Bg + kt, Bl);
    gl16(Bg + 64 * KTOT + kt, Bl + 2048);
    __syncthreads();                             // compiler drains vmcnt before barrier
    bf16x8 af[4], bfr[4];
#pragma unroll
    for (int i = 0; i < 4; ++i)
      af[i] = *(const bf16x8*)(Ash + (wm * 64 + i * 16 + am) * 32 + ak);
#pragma unroll
    for (int j = 0; j < 4; ++j)
      bfr[j] = *(const bf16x8*)(Bsh + (wn * 64 + j * 16 + am) * 32 + ak);
#pragma unroll
    for (int i = 0; i < 4; ++i)
#pragma unroll
      for (int j = 0; j < 4; ++j)
        acc[i][j] = __builtin_amdgcn_mfma_f32_16x16x32_bf16(af[i], bfr[j], acc[i][j], 0, 0, 0);
  }

  // C/D layout (verified): col n = lane&15, row m = (lane>>4)*4 + reg
  int rbase = row0 + wm * 64 + (lane >> 4) * 4;
  int nbase = n0 + wn * 64 + (lane & 15);
  if constexpr (EPI == 0) {
    unsigned short* Hp = (unsigned short*)Cout;
    const float* bp = bias + (size_t)e * NTOT;
#pragma unroll
    for (int i = 0; i < 4; ++i) {
#pragma unroll
      for (int j = 0; j < 4; ++j) {
        int n = nbase + j * 16;
        float bv = bp[n];
#pragma unroll
        for (int rg = 0; rg < 4; ++rg) {
          int m = rbase + i * 16 + rg;
          float v = acc[i][j][rg] + bv;
          v = 0.5f * v * (1.f + erff(v * 0.70710678118654752f));   // exact gelu
          Hp[(size_t)m * NTOT + n] = f2bf(v);
        }
      }
    }
  } else {
    float* Yp = (float*)Cout;
    const float* bp = bias + (size_t)e * NTOT;
#pragma unroll
    for (int i = 0; i < 4; ++i) {
#pragma unroll
      for (int rg = 0; rg < 4; ++rg) {
        int m = rbase + i * 16 + rg;
        float wt = wt_of_row[m];
#pragma unroll
        for (int j = 0; j < 4; ++j) {
          int n = nbase + j * 16;
          Yp[(size_t)m * NTOT + n] = (acc[i][j][rg] + bp[n]) * wt;
        }
      }
    }
  }
}

// ---------------- combine: out[t] = y[row0(t)] + y[row1(t)] ------------------
__global__ __launch_bounds__(256) void combine_k(const float* __restrict__ y,
                                                 const int* __restrict__ row_of,
                                                 float* __restrict__ out) {
  int t = blockIdx.x;
  int r0 = row_of[t * 2], r1 = row_of[t * 2 + 1];
  int c = threadIdx.x * 4;
  float4 a = *(const float4*)(y + (size_t)r0 * DIM + c);
  float4 b = *(const float4*)(y + (size_t)r1 * DIM + c);
  *(float4*)(out + (size_t)t * DIM + c) =
      make_float4(a.x + b.x, a.y + b.y, a.z + b.z, a.w + b.w);
}

extern "C" void kernel_launch(void* const* d_in, const int* in_sizes, int n_in,
                              void* d_out, int out_size, void* d_ws, size_t ws_size,
                              hipStream_t stream) {
  const float* x  = (const float*)d_in[0];
  const float* Wr = (const float*)d_in[1];
  const float* br = (const float*)d_in[2];
  const float* W1 = (const float*)d_in[3];
  const float* b1 = (const float*)d_in[4];
  const float* W2 = (const float*)d_in[5];
  const float* b2 = (const float*)d_in[6];
  float* out = (float*)d_out;

  char* base = (char*)d_ws;
  size_t off = 0;
  auto carve = [&](size_t bytes) -> void* {
    void* r = base + off;
    off = (off + bytes + 255) & ~(size_t)255;
    return r;
  };
  int*            meta       = (int*)carve(26 * 4);
  int2*           top_i      = (int2*)carve((size_t)T_TOK * 8);
  float2*         top_w      = (float2*)carve((size_t)T_TOK * 8);
  int*            row_of     = (int*)carve((size_t)T_TOK * 2 * 4);
  int*            tok_of_row = (int*)carve((size_t)MAXR * 4);
  float*          wt_of_row  = (float*)carve((size_t)MAXR * 4);
  unsigned short* xg         = (unsigned short*)carve((size_t)MAXR * DIM * 2);
  unsigned short* W1bT       = (unsigned short*)carve((size_t)NEXP * DIM * HID * 2);
  unsigned short* W2bT       = (unsigned short*)carve((size_t)NEXP * DIM * HID * 2);
  unsigned short* hbuf       = (unsigned short*)carve((size_t)MAXR * HID * 2);
  float*          ybuf       = (float*)carve((size_t)MAXR * DIM * 4);
  if (off > ws_size) {
    fprintf(stderr, "kernel_launch: ws_size too small: need %zu have %zu\n", off, ws_size);
    return;
  }

  hipMemsetAsync(meta, 0, 26 * 4, stream);
  hipLaunchKernelGGL(transpose_convert_k, dim3(HID / 32, DIM / 32, NEXP), dim3(256), 0, stream,
                     W1, W1bT, DIM, HID);                 // W1[e][D][H] -> [e][H][D]
  hipLaunchKernelGGL(transpose_convert_k, dim3(DIM / 32, HID / 32, NEXP), dim3(256), 0, stream,
                     W2, W2bT, HID, DIM);                 // W2[e][H][D] -> [e][D][H]
  hipLaunchKernelGGL(fill_k, dim3((MAXR + 255) / 256), dim3(256), 0, stream,
                     tok_of_row, wt_of_row);
  hipLaunchKernelGGL(router_k, dim3(T_TOK / 4), dim3(256), 0, stream,
                     x, Wr, br, meta, top_i, top_w);
  hipLaunchKernelGGL(prefix_k, dim3(1), dim3(64), 0, stream, meta);
  hipLaunchKernelGGL(scatter_k, dim3(T_TOK / 256), dim3(256), 0, stream,
                     top_i, top_w, meta, row_of, tok_of_row, wt_of_row);
  hipLaunchKernelGGL(gather_k, dim3(MAXR), dim3(256), 0, stream, x, tok_of_row, meta, xg);
  hipLaunchKernelGGL((gemm_k<DIM, HID, 0>), dim3(MAXR / 128 * (HID / 128)), dim3(256), 0, stream,
                     xg, W1bT, b1, meta, wt_of_row, (void*)hbuf);
  hipLaunchKernelGGL((gemm_k<HID, DIM, 1>), dim3(MAXR / 128 * (DIM / 128)), dim3(256), 0, stream,
                     hbuf, W2bT, b2, meta, wt_of_row, (void*)ybuf);
  hipLaunchKernelGGL(combine_k, dim3(T_TOK), dim3(256), 0, stream, ybuf, row_of, out);
}